// Round 13
// baseline (247.789 us; speedup 1.0000x reference)
//
#include <hip/hip_runtime.h>

#define BB 16
#define QQ 900
#define QP 960           // padded column count = 15*64 (pad cols hold +INF)
#define VIRT QP          // virtual start column index
#define CC 92
#define TT 100
#define INFF 1e18f
#define NK 15            // QP / 64

// ---- DPP wave64 reductions (VALU latency, no DS ops) -------------------
#define DPP_STEP_F(x, ctrl, OP)                                             \
  do {                                                                      \
    float _o = __int_as_float(__builtin_amdgcn_update_dpp(                  \
        __float_as_int(x), __float_as_int(x), (ctrl), 0xF, 0xF, false));    \
    (x) = OP((x), _o);                                                      \
  } while (0)

__device__ __forceinline__ float wave_fmax63(float x) {
  DPP_STEP_F(x, 0xB1, fmaxf);
  DPP_STEP_F(x, 0x4E, fmaxf);
  DPP_STEP_F(x, 0x141, fmaxf);
  DPP_STEP_F(x, 0x140, fmaxf);
  DPP_STEP_F(x, 0x142, fmaxf);
  DPP_STEP_F(x, 0x143, fmaxf);
  return x;
}
__device__ __forceinline__ float wave_fmin63(float x) {
  DPP_STEP_F(x, 0xB1, fminf);
  DPP_STEP_F(x, 0x4E, fminf);
  DPP_STEP_F(x, 0x141, fminf);
  DPP_STEP_F(x, 0x140, fminf);
  DPP_STEP_F(x, 0x142, fminf);
  DPP_STEP_F(x, 0x143, fminf);
  return x;
}
__device__ __forceinline__ float wave_fadd63(float x) {
#define ADDF(a, b) ((a) + (b))
  DPP_STEP_F(x, 0xB1, ADDF);
  DPP_STEP_F(x, 0x4E, ADDF);
  DPP_STEP_F(x, 0x141, ADDF);
  DPP_STEP_F(x, 0x140, ADDF);
  DPP_STEP_F(x, 0x142, ADDF);
  DPP_STEP_F(x, 0x143, ADDF);
#undef ADDF
  return x;
}
__device__ __forceinline__ int wave_imin63(int x) {
  {int _o=__builtin_amdgcn_update_dpp(x,x,0xB1,0xF,0xF,false); x=_o<x?_o:x;}
  {int _o=__builtin_amdgcn_update_dpp(x,x,0x4E,0xF,0xF,false); x=_o<x?_o:x;}
  {int _o=__builtin_amdgcn_update_dpp(x,x,0x141,0xF,0xF,false);x=_o<x?_o:x;}
  {int _o=__builtin_amdgcn_update_dpp(x,x,0x140,0xF,0xF,false);x=_o<x?_o:x;}
  {int _o=__builtin_amdgcn_update_dpp(x,x,0x142,0xF,0xF,false);x=_o<x?_o:x;}
  {int _o=__builtin_amdgcn_update_dpp(x,x,0x143,0xF,0xF,false);x=_o<x?_o:x;}
  return x;
}

__device__ __forceinline__ float readlane_f(float x, int l) {
  return __int_as_float(__builtin_amdgcn_readlane(__float_as_int(x), l));
}

// p[] packed as bytes across 4 VGPRs: column j -> lane (j&63), slot (j>>6),
// reg (slot>>2), byte (slot&3). Values <= TT=100 fit a byte.
__device__ __forceinline__ int p_get(unsigned a, unsigned b, unsigned c,
                                     unsigned d, int j) {
  const int l = j & 63, kq = j >> 6;
  unsigned r0 = (unsigned)__builtin_amdgcn_readlane((int)a, l);
  unsigned r1 = (unsigned)__builtin_amdgcn_readlane((int)b, l);
  unsigned r2 = (unsigned)__builtin_amdgcn_readlane((int)c, l);
  unsigned r3 = (unsigned)__builtin_amdgcn_readlane((int)d, l);
  unsigned r = (kq < 8) ? (kq < 4 ? r0 : r1) : (kq < 12 ? r2 : r3);
  return (int)((r >> ((kq & 3) * 8)) & 0xFFu);
}

#define P_SET(jj, val)                                                      \
  do {                                                                      \
    const int _j = (jj); const int _kq = _j >> 6;                           \
    const unsigned _sh = (unsigned)((_kq & 3) * 8);                         \
    const unsigned _nm = ~(0xFFu << _sh);                                   \
    const unsigned _in = ((unsigned)(val) & 0xFFu) << _sh;                  \
    const bool _own = (lane == (_j & 63));                                  \
    if (_kq < 4)       { if (_own) p4a = (p4a & _nm) | _in; }               \
    else if (_kq < 8)  { if (_own) p4b = (p4b & _nm) | _in; }               \
    else if (_kq < 12) { if (_own) p4c = (p4c & _nm) | _in; }               \
    else               { if (_own) p4d = (p4d & _nm) | _in; }               \
  } while (0)

// ---------------- cost kernel: one WAVE per (b,q) ----------------
__global__ __launch_bounds__(64) void cost_kernel(
    const float* __restrict__ logits,   // [B][Q][C]
    const float* __restrict__ pboxes,   // [B][Q][4]
    const int*   __restrict__ tlabels,  // [B][T]
    const float* __restrict__ tboxes,   // [B][T][4]
    float* __restrict__ cost,           // [B][Q][T]
    float* __restrict__ costT,          // [B][T][ctp] or nullptr
    int ctp)
{
  const int bq   = blockIdx.x;          // b*QQ + q
  const int b    = bq / QQ;
  const int q    = bq - b * QQ;
  const int lane = threadIdx.x;

  __shared__ float sl[CC];

  const float a = logits[(size_t)bq * CC + lane];
  const float bb2 = (lane < CC - 64)
                        ? logits[(size_t)bq * CC + 64 + lane]
                        : -3.402823466e38f;

  float mx = fmaxf(a, bb2);
  mx = wave_fmax63(mx);
  const float m = readlane_f(mx, 63);

  const float e0 = expf(a - m);
  const float e1 = (lane < CC - 64) ? expf(bb2 - m) : 0.0f;
  sl[lane] = e0;
  if (lane < CC - 64) sl[64 + lane] = e1;

  float sm = e0 + e1;
  sm = wave_fadd63(sm);
  const float ssum = readlane_f(sm, 63);

  const float4 pbv = ((const float4*)pboxes)[bq];
  const float pax1 = pbv.x - 0.5f * pbv.z, pay1 = pbv.y - 0.5f * pbv.w;
  const float pax2 = pbv.x + 0.5f * pbv.z, pay2 = pbv.y + 0.5f * pbv.w;
  const float area_a = (pax2 - pax1) * (pay2 - pay1);

  for (int t = lane; t < TT; t += 64) {
    const int lab = tlabels[b * TT + t];
    const float cc = -(sl[lab] / ssum);

    const float4 tb = ((const float4*)tboxes)[b * TT + t];
    const float cbox = fabsf(pbv.x - tb.x) + fabsf(pbv.y - tb.y) +
                       fabsf(pbv.z - tb.z) + fabsf(pbv.w - tb.w);

    const float bx1 = tb.x - 0.5f * tb.z, by1 = tb.y - 0.5f * tb.w;
    const float bx2 = tb.x + 0.5f * tb.z, by2 = tb.y + 0.5f * tb.w;
    const float area_b = (bx2 - bx1) * (by2 - by1);

    const float ltx = fmaxf(pax1, bx1), lty = fmaxf(pay1, by1);
    const float rbx = fminf(pax2, bx2), rby = fminf(pay2, by2);
    const float iw = fmaxf(rbx - ltx, 0.0f), ih = fmaxf(rby - lty, 0.0f);
    const float inter = iw * ih;
    const float uni = area_a + area_b - inter;
    const float iou = inter / uni;

    const float cx1 = fminf(pax1, bx1), cy1 = fminf(pay1, by1);
    const float cx2 = fmaxf(pax2, bx2), cy2 = fmaxf(pay2, by2);
    const float cw = fmaxf(cx2 - cx1, 0.0f), ch = fmaxf(cy2 - cy1, 0.0f);
    const float ac = cw * ch;
    const float giou = iou - (ac - uni) / ac;

    const float cval = 5.0f * cbox + cc - 2.0f * giou;
    cost[(size_t)bq * TT + t] = cval;
    if (ctp) costT[((size_t)b * TT + t) * ctp + q] = cval;
  }
  // fill pad columns with +INF (never win the argmin)
  if (ctp == QP && q < QP - QQ) {
    for (int t = lane; t < TT; t += 64)
      costT[((size_t)b * TT + t) * QP + QQ + q] = INFF;
  }
}

// ------- specialized hungarian: padded costT, ONE WAVE per batch --------
// r13: SPECULATIVE SWEEP + COMMIT. Single-step rows (argmin column
// unmatched, ~94%) leave v unchanged and only set p[j1]=i, u[i]=delta.
// So all remaining rows' first-step argmins (min_j c[r][j]-v[j], u[r]=0)
// are INDEPENDENT: compute them in a pipelined sweep (cross-row ILP,
// latency hidden), then commit serially; on the first collision (argmin
// column already matched) run the exact Dijkstra for that row (v changes)
// and re-sweep the remainder. Bitwise-identical math -> identical
// assignment. Expected fallbacks ~6.
__global__ void __launch_bounds__(64)
hungarianT_kernel(
    const float* __restrict__ ct,      // [B][T][QP] padded transposed cost
    float* __restrict__ out_q,         // [B][T]
    float* __restrict__ out_t)         // [B][T]
{
  const int b    = blockIdx.x;
  const int lane = threadIdx.x;

  __shared__ int way_lds[QP];
  __shared__ int qpt[TT];

  const float* __restrict__ base = ct + (size_t)b * TT * QP;

  // invalidate way stamps (decode: (raw>>12)==row; -1 never matches)
#pragma unroll
  for (int k = 0; k < NK; ++k) way_lds[k * 64 + lane] = -1;

  unsigned p4a = 0x64646464u, p4b = 0x64646464u;   // all bytes = TT = 100
  unsigned p4c = 0x64646464u, p4d = 0x64646464u;

  float u0 = 0.0f, u1 = 0.0f;   // u[lane], u[64+lane]
  float v[NK];
#pragma unroll
  for (int k = 0; k < NK; ++k) v[k] = 0.0f;

  int rbase = 0;
  for (int epoch = 0; epoch <= TT && rbase < TT; ++epoch) {
    // ---------------- SWEEP rows rbase..TT-1 (independent) --------------
    // result for row rbase+off stashed in lane off (off<64) / off-64
    float valv0 = 0.0f, valv1 = 0.0f;
    int   colv0 = 0,    colv1 = 0;

    float cn[NK];
    {
      const float* __restrict__ rp = base + (size_t)rbase * QP;
#pragma unroll
      for (int k = 0; k < NK; ++k) cn[k] = rp[k * 64 + lane];
    }
    for (int s = rbase; s < TT; ++s) {
      float cc[NK];
#pragma unroll
      for (int k = 0; k < NK; ++k) cc[k] = cn[k];
      if (s + 1 < TT) {                       // software pipeline depth 1
        const float* __restrict__ rp = base + (size_t)(s + 1) * QP;
#pragma unroll
        for (int k = 0; k < NK; ++k) cn[k] = rp[k * 64 + lane];
      }
      // per-lane argmin over 15 slots (u[s]==0 for unstarted rows)
      float lmin  = INFF;
      int   kbest = 0;
#pragma unroll
      for (int k = 0; k < NK; ++k) {
        const float cur = cc[k] - v[k];
        if (cur < lmin) { lmin = cur; kbest = k; }
      }
      const int lidx = (kbest << 6) + lane;
      // wave reduce: value (6 DPP fmin) then winner lane via ballot
      float red = wave_fmin63(lmin);
      const float delta = readlane_f(red, 63);
      const unsigned long long bm = __ballot(lmin == delta);
      const int wl = (int)(__ffsll((long long)bm) - 1);
      const int j1 = __builtin_amdgcn_readlane(lidx, wl);
      // stash
      const int off = s - rbase;
      if (off < 64) { if (lane == off)      { valv0 = delta; colv0 = j1; } }
      else          { if (lane == off - 64) { valv1 = delta; colv1 = j1; } }
    }

    // ---------------- COMMIT in row order -------------------------------
    int sfb = -1;
    for (int s = rbase; s < TT; ++s) {
      const int off = s - rbase;
      float sv; int sc;
      if (off < 64) { sv = readlane_f(valv0, off);      sc = __builtin_amdgcn_readlane(colv0, off); }
      else          { sv = readlane_f(valv1, off - 64); sc = __builtin_amdgcn_readlane(colv1, off - 64); }
      const int pm = p_get(p4a, p4b, p4c, p4d, sc);
      if (pm != TT) { sfb = s; break; }      // collision -> full Dijkstra
      P_SET(sc, s);                          // commit single-step row
      u0 = (lane == s)      ? sv : u0;       // u[s] = delta
      u1 = (lane == s - 64) ? sv : u1;
    }
    if (sfb < 0) { rbase = TT; break; }      // all remaining rows committed

    // ---------------- FALLBACK: exact Dijkstra for row sfb --------------
    {
      const int s = sfb;
      float c2[NK];
      {
        const float* __restrict__ rp = base + (size_t)s * QP;
#pragma unroll
        for (int k = 0; k < NK; ++k) c2[k] = rp[k * 64 + lane];
      }
      float minv[NK];
#pragma unroll
      for (int k = 0; k < NK; ++k) minv[k] = INFF;
      unsigned umask = 0;                    // bits0-14 used cols; 30/31 rows
      const int stamp = s << 12;

      int i0 = s;
      int j0 = VIRT;
      int jfin;

      float us_ = (i0 < 64) ? u0 : u1;
      float ui0 = readlane_f(us_, i0 & 63);  // u[s] == 0 here (row untouched)

      for (int step = 0; step < 256; ++step) {   // bound: hang insurance
        const bool first = (j0 == VIRT);
        if (i0 == lane)      umask |= (1u << 30);
        if (i0 == 64 + lane) umask |= (1u << 31);
        if (!first && (j0 & 63) == lane) umask |= (1u << (j0 >> 6));

        float lmin  = INFF;
        int   kbest = 0;
#pragma unroll
        for (int k = 0; k < NK; ++k) {
          const bool  uk  = (umask >> k) & 1u;
          const float cur = c2[k] - ui0 - v[k];
          const bool  imp = !uk && (cur < minv[k]);
          if (imp) {
            minv[k] = cur;
            if (!first) way_lds[k * 64 + lane] = stamp | j0;
          }
          const float eff = uk ? INFF : minv[k];
          if (eff < lmin) { lmin = eff; kbest = k; }
        }
        const int lidx = (kbest << 6) + lane;

        float red = wave_fmin63(lmin);
        const float delta = readlane_f(red, 63);
        const unsigned long long bm = __ballot(lmin == delta);
        const int wl = (int)(__ffsll((long long)bm) - 1);
        const int j1 = __builtin_amdgcn_readlane(lidx, wl);

        const int  i0n = p_get(p4a, p4b, p4c, p4d, j1);
        const bool fin = (i0n == TT);

        if (!fin) {
          const float* __restrict__ prow = base + (size_t)i0n * QP;
#pragma unroll
          for (int k = 0; k < NK; ++k) c2[k] = prow[k * 64 + lane];
        }

        u0 += ((umask >> 30) & 1u) ? delta : 0.0f;
        u1 += (umask >> 31)        ? delta : 0.0f;
#pragma unroll
        for (int k = 0; k < NK; ++k)
          v[k] -= ((umask >> k) & 1u) ? delta : 0.0f;
        if (!fin) {
#pragma unroll
          for (int k = 0; k < NK; ++k)
            minv[k] -= ((umask >> k) & 1u) ? 0.0f : delta;
        }

        if (fin) { jfin = j1; break; }
        float us2 = (i0n < 64) ? u0 : u1;
        ui0 = readlane_f(us2, i0n & 63);
        j0 = j1;
        i0 = i0n;
      }

      // augment
      if (j0 == VIRT) {
        P_SET(jfin, s);
      } else {
        int j = jfin;
        for (int hop = 0; hop < 256 && j != VIRT; ++hop) {
          int raw = way_lds[j];
          raw = __builtin_amdgcn_readfirstlane(raw);
          const int jn = ((raw >> 12) == s) ? (raw & 0xFFF) : VIRT;
          const int pj = (jn == VIRT) ? s : p_get(p4a, p4b, p4c, p4d, jn);
          P_SET(j, pj);
          j = jn;
        }
      }
    }
    rbase = sfb + 1;                         // re-sweep the remainder
  }

  // q_per_t: query assigned to each target row (pads keep p == TT)
#pragma unroll
  for (int k = 0; k < NK; ++k) {
    const unsigned reg = (k < 4) ? p4a : (k < 8) ? p4b : (k < 12) ? p4c : p4d;
    const int r = (int)((reg >> ((k & 3) * 8)) & 0xFFu);
    const int j = k * 64 + lane;
    if (r < TT) qpt[r] = j;
  }
  __syncthreads();

  // argsort(q_per_t) via rank counting (values are distinct)
  for (int t = lane; t < TT; t += 64) {
    const int myq = qpt[t];
    int rank = 0;
    for (int t2 = 0; t2 < TT; ++t2) rank += (qpt[t2] < myq) ? 1 : 0;
    out_q[b * TT + rank] = (float)myq;
    out_t[b * TT + rank] = (float)t;
  }
}

// ---------------- generic fallback (r7 kernel, verified) ----------------
__global__ void __launch_bounds__(64)
hungarian_kernel(
    const float* __restrict__ cost,    // [B][Q][T]
    const float* __restrict__ costT,   // [B][T][QQ] or nullptr
    float* __restrict__ out_q,
    float* __restrict__ out_t)
{
  const int b    = blockIdx.x;
  const int lane = threadIdx.x;

  __shared__ int p_lds[QQ + 1];
  __shared__ int way_lds[QQ];
  __shared__ int qpt[TT];

  const float* base;
  size_t rs, cs;
  if (costT) { base = costT + (size_t)b * TT * QQ; rs = QQ; cs = 1; }
  else       { base = cost  + (size_t)b * QQ * TT; rs = 1;  cs = TT; }

  for (int j = lane; j <= QQ; j += 64) p_lds[j] = TT;

  float u0 = 0.0f, u1 = 0.0f;
  float v[NK];
#pragma unroll
  for (int k = 0; k < NK; ++k) v[k] = 0.0f;

  float c[NK];
#pragma unroll
  for (int k = 0; k < NK; ++k) {
    const int j = k * 64 + lane;
    c[k] = (j < QQ) ? base[(size_t)j * cs] : 0.0f;
  }

  for (int i = 0; i < TT; ++i) {
    p_lds[QQ] = i;

    float minv[NK];
#pragma unroll
    for (int k = 0; k < NK; ++k) minv[k] = INFF;
    unsigned umask = 0;
    bool t0 = false, t1 = false;

    int i0 = i;
    int j0 = QQ;
    int jfin;

    float us = (i0 < 64) ? u0 : u1;
    float ui0 = readlane_f(us, i0 & 63);

    while (true) {
      t0 = t0 || (i0 == lane);
      t1 = t1 || (i0 == 64 + lane);
      if (j0 != QQ) {
        if ((j0 & 63) == lane) umask |= (1u << (j0 >> 6));
      }

      float lmin = INFF;
      int   lidx = QQ;
#pragma unroll
      for (int k = 0; k < NK; ++k) {
        const int j = k * 64 + lane;
        if (j < QQ && !((umask >> k) & 1u)) {
          const float cur = c[k] - ui0 - v[k];
          if (cur < minv[k]) { minv[k] = cur; way_lds[j] = j0; }
          if (minv[k] < lmin) { lmin = minv[k]; lidx = j; }
        }
      }

      float red = wave_fmin63(lmin);
      const float delta = readlane_f(red, 63);
      int cand = (lmin == delta) ? lidx : 0x7FFFFFFF;
      int redi = wave_imin63(cand);
      const int j1 = __builtin_amdgcn_readlane(redi, 63);

      int i0n = p_lds[j1];
      i0n = __builtin_amdgcn_readfirstlane(i0n);
      const bool fin = (i0n == TT);

      u0 += t0 ? delta : 0.0f;
      u1 += t1 ? delta : 0.0f;
#pragma unroll
      for (int k = 0; k < NK; ++k) {
        const bool uk = (umask >> k) & 1u;
        v[k]    -= uk ? delta : 0.0f;
        minv[k] -= uk ? 0.0f  : delta;
      }

      if (!fin) {
        float us2 = (i0n < 64) ? u0 : u1;
        ui0 = readlane_f(us2, i0n & 63);
#pragma unroll
        for (int k = 0; k < NK; ++k) {
          const int j = k * 64 + lane;
          if (j < QQ) c[k] = base[(size_t)i0n * rs + (size_t)j * cs];
        }
      }
      asm volatile("" ::: "memory");

      if (fin) { jfin = j1; break; }
      j0 = j1;
      i0 = i0n;
    }

    if (i + 1 < TT) {
#pragma unroll
      for (int k = 0; k < NK; ++k) {
        const int jj = k * 64 + lane;
        if (jj < QQ) c[k] = base[(size_t)(i + 1) * rs + (size_t)jj * cs];
      }
    }

    int j = jfin;
    while (j != QQ) {
      const int jn = way_lds[j];
      const int pj = p_lds[jn];
      p_lds[j] = pj;
      j = jn;
    }
    asm volatile("" ::: "memory");
  }

#pragma unroll
  for (int k = 0; k < NK; ++k) {
    const int j = k * 64 + lane;
    if (j < QQ) {
      const int r = p_lds[j];
      if (r < TT) qpt[r] = j;
    }
  }
  __syncthreads();

  for (int t = lane; t < TT; t += 64) {
    const int myq = qpt[t];
    int rank = 0;
    for (int t2 = 0; t2 < TT; ++t2) rank += (qpt[t2] < myq) ? 1 : 0;
    out_q[b * TT + rank] = (float)myq;
    out_t[b * TT + rank] = (float)t;
  }
}

extern "C" void kernel_launch(void* const* d_in, const int* in_sizes, int n_in,
                              void* d_out, int out_size, void* d_ws, size_t ws_size,
                              hipStream_t stream) {
  const float* logits  = (const float*)d_in[0];
  const float* pboxes  = (const float*)d_in[1];
  const int*   tlabels = (const int*)d_in[2];
  const float* tboxes  = (const float*)d_in[3];

  float* out  = (float*)d_out;
  float* cost = out;                               // [B][Q][T]
  float* oq   = out + (size_t)BB * QQ * TT;        // [B][T]
  float* ot   = oq + (size_t)BB * TT;              // [B][T]

  const size_t padded_bytes = (size_t)BB * TT * QP * sizeof(float);
  const size_t plain_bytes  = (size_t)BB * TT * QQ * sizeof(float);

  if (ws_size >= padded_bytes) {
    float* costT = (float*)d_ws;
    hipLaunchKernelGGL(cost_kernel, dim3(BB * QQ), dim3(64), 0, stream,
                       logits, pboxes, tlabels, tboxes, cost, costT, QP);
    hipLaunchKernelGGL(hungarianT_kernel, dim3(BB), dim3(64), 0, stream,
                       costT, oq, ot);
  } else if (ws_size >= plain_bytes) {
    float* costT = (float*)d_ws;
    hipLaunchKernelGGL(cost_kernel, dim3(BB * QQ), dim3(64), 0, stream,
                       logits, pboxes, tlabels, tboxes, cost, costT, QQ);
    hipLaunchKernelGGL(hungarian_kernel, dim3(BB), dim3(64), 0, stream,
                       cost, costT, oq, ot);
  } else {
    hipLaunchKernelGGL(cost_kernel, dim3(BB * QQ), dim3(64), 0, stream,
                       logits, pboxes, tlabels, tboxes, cost, (float*)nullptr, 0);
    hipLaunchKernelGGL(hungarian_kernel, dim3(BB), dim3(64), 0, stream,
                       cost, (const float*)nullptr, oq, ot);
  }
}

// Round 14
// 235.395 us; speedup vs baseline: 1.0527x; 1.0527x over previous
//
#include <hip/hip_runtime.h>

#define BB 16
#define QQ 900
#define QP 960           // padded column count = 15*64 (pad cols hold +INF)
#define VIRT QP          // virtual start column index
#define CC 92
#define TT 100
#define INFF 1e18f
#define NK 15            // QP / 64

// ---- DPP wave64 reductions (VALU latency, no DS ops) -------------------
#define DPP_STEP_F(x, ctrl, OP)                                             \
  do {                                                                      \
    float _o = __int_as_float(__builtin_amdgcn_update_dpp(                  \
        __float_as_int(x), __float_as_int(x), (ctrl), 0xF, 0xF, false));    \
    (x) = OP((x), _o);                                                      \
  } while (0)

__device__ __forceinline__ float wave_fmax63(float x) {
  DPP_STEP_F(x, 0xB1, fmaxf);
  DPP_STEP_F(x, 0x4E, fmaxf);
  DPP_STEP_F(x, 0x141, fmaxf);
  DPP_STEP_F(x, 0x140, fmaxf);
  DPP_STEP_F(x, 0x142, fmaxf);
  DPP_STEP_F(x, 0x143, fmaxf);
  return x;
}
__device__ __forceinline__ float wave_fmin63(float x) {
  DPP_STEP_F(x, 0xB1, fminf);
  DPP_STEP_F(x, 0x4E, fminf);
  DPP_STEP_F(x, 0x141, fminf);
  DPP_STEP_F(x, 0x140, fminf);
  DPP_STEP_F(x, 0x142, fminf);
  DPP_STEP_F(x, 0x143, fminf);
  return x;
}
__device__ __forceinline__ float wave_fadd63(float x) {
#define ADDF(a, b) ((a) + (b))
  DPP_STEP_F(x, 0xB1, ADDF);
  DPP_STEP_F(x, 0x4E, ADDF);
  DPP_STEP_F(x, 0x141, ADDF);
  DPP_STEP_F(x, 0x140, ADDF);
  DPP_STEP_F(x, 0x142, ADDF);
  DPP_STEP_F(x, 0x143, ADDF);
#undef ADDF
  return x;
}
__device__ __forceinline__ int wave_imin63(int x) {
  {int _o=__builtin_amdgcn_update_dpp(x,x,0xB1,0xF,0xF,false); x=_o<x?_o:x;}
  {int _o=__builtin_amdgcn_update_dpp(x,x,0x4E,0xF,0xF,false); x=_o<x?_o:x;}
  {int _o=__builtin_amdgcn_update_dpp(x,x,0x141,0xF,0xF,false);x=_o<x?_o:x;}
  {int _o=__builtin_amdgcn_update_dpp(x,x,0x140,0xF,0xF,false);x=_o<x?_o:x;}
  {int _o=__builtin_amdgcn_update_dpp(x,x,0x142,0xF,0xF,false);x=_o<x?_o:x;}
  {int _o=__builtin_amdgcn_update_dpp(x,x,0x143,0xF,0xF,false);x=_o<x?_o:x;}
  return x;
}

__device__ __forceinline__ float readlane_f(float x, int l) {
  return __int_as_float(__builtin_amdgcn_readlane(__float_as_int(x), l));
}

// stage one padded cost row (960 f32 = 3840 B) into LDS.
// HW-verified widths only: 3x16B (floats 0..767) + 3x4B (768..959).
__device__ __forceinline__ void stage_row(const float* __restrict__ row,
                                          float* buf, int lane) {
  typedef __attribute__((address_space(1))) const void gv_t;
  typedef __attribute__((address_space(3))) void lv_t;
  __builtin_amdgcn_global_load_lds((gv_t*)(row + lane * 4),       (lv_t*)(buf),       16, 0, 0);
  __builtin_amdgcn_global_load_lds((gv_t*)(row + 256 + lane * 4), (lv_t*)(buf + 256), 16, 0, 0);
  __builtin_amdgcn_global_load_lds((gv_t*)(row + 512 + lane * 4), (lv_t*)(buf + 512), 16, 0, 0);
  __builtin_amdgcn_global_load_lds((gv_t*)(row + 768 + lane),     (lv_t*)(buf + 768), 4, 0, 0);
  __builtin_amdgcn_global_load_lds((gv_t*)(row + 832 + lane),     (lv_t*)(buf + 832), 4, 0, 0);
  __builtin_amdgcn_global_load_lds((gv_t*)(row + 896 + lane),     (lv_t*)(buf + 896), 4, 0, 0);
}

// p[] packed as bytes across 4 VGPRs: column j -> lane (j&63), slot (j>>6),
// reg (slot>>2), byte (slot&3). Values <= TT=100 fit a byte.
__device__ __forceinline__ int p_get(unsigned a, unsigned b, unsigned c,
                                     unsigned d, int j) {
  const int l = j & 63, kq = j >> 6;
  unsigned r0 = (unsigned)__builtin_amdgcn_readlane((int)a, l);
  unsigned r1 = (unsigned)__builtin_amdgcn_readlane((int)b, l);
  unsigned r2 = (unsigned)__builtin_amdgcn_readlane((int)c, l);
  unsigned r3 = (unsigned)__builtin_amdgcn_readlane((int)d, l);
  unsigned r = (kq < 8) ? (kq < 4 ? r0 : r1) : (kq < 12 ? r2 : r3);
  return (int)((r >> ((kq & 3) * 8)) & 0xFFu);
}

#define P_SET(jj, val)                                                      \
  do {                                                                      \
    const int _j = (jj); const int _kq = _j >> 6;                           \
    const unsigned _sh = (unsigned)((_kq & 3) * 8);                         \
    const unsigned _nm = ~(0xFFu << _sh);                                   \
    const unsigned _in = ((unsigned)(val) & 0xFFu) << _sh;                  \
    const bool _own = (lane == (_j & 63));                                  \
    if (_kq < 4)       { if (_own) p4a = (p4a & _nm) | _in; }               \
    else if (_kq < 8)  { if (_own) p4b = (p4b & _nm) | _in; }               \
    else if (_kq < 12) { if (_own) p4c = (p4c & _nm) | _in; }               \
    else               { if (_own) p4d = (p4d & _nm) | _in; }               \
  } while (0)

// ---------------- cost kernel: one WAVE per (b,q) ----------------
__global__ __launch_bounds__(64) void cost_kernel(
    const float* __restrict__ logits,   // [B][Q][C]
    const float* __restrict__ pboxes,   // [B][Q][4]
    const int*   __restrict__ tlabels,  // [B][T]
    const float* __restrict__ tboxes,   // [B][T][4]
    float* __restrict__ cost,           // [B][Q][T]
    float* __restrict__ costT,          // [B][T][ctp] or nullptr
    int ctp)
{
  const int bq   = blockIdx.x;          // b*QQ + q
  const int b    = bq / QQ;
  const int q    = bq - b * QQ;
  const int lane = threadIdx.x;

  __shared__ float sl[CC];

  const float a = logits[(size_t)bq * CC + lane];
  const float bb2 = (lane < CC - 64)
                        ? logits[(size_t)bq * CC + 64 + lane]
                        : -3.402823466e38f;

  float mx = fmaxf(a, bb2);
  mx = wave_fmax63(mx);
  const float m = readlane_f(mx, 63);

  const float e0 = expf(a - m);
  const float e1 = (lane < CC - 64) ? expf(bb2 - m) : 0.0f;
  sl[lane] = e0;
  if (lane < CC - 64) sl[64 + lane] = e1;

  float sm = e0 + e1;
  sm = wave_fadd63(sm);
  const float ssum = readlane_f(sm, 63);

  const float4 pbv = ((const float4*)pboxes)[bq];
  const float pax1 = pbv.x - 0.5f * pbv.z, pay1 = pbv.y - 0.5f * pbv.w;
  const float pax2 = pbv.x + 0.5f * pbv.z, pay2 = pbv.y + 0.5f * pbv.w;
  const float area_a = (pax2 - pax1) * (pay2 - pay1);

  for (int t = lane; t < TT; t += 64) {
    const int lab = tlabels[b * TT + t];
    const float cc = -(sl[lab] / ssum);

    const float4 tb = ((const float4*)tboxes)[b * TT + t];
    const float cbox = fabsf(pbv.x - tb.x) + fabsf(pbv.y - tb.y) +
                       fabsf(pbv.z - tb.z) + fabsf(pbv.w - tb.w);

    const float bx1 = tb.x - 0.5f * tb.z, by1 = tb.y - 0.5f * tb.w;
    const float bx2 = tb.x + 0.5f * tb.z, by2 = tb.y + 0.5f * tb.w;
    const float area_b = (bx2 - bx1) * (by2 - by1);

    const float ltx = fmaxf(pax1, bx1), lty = fmaxf(pay1, by1);
    const float rbx = fminf(pax2, bx2), rby = fminf(pay2, by2);
    const float iw = fmaxf(rbx - ltx, 0.0f), ih = fmaxf(rby - lty, 0.0f);
    const float inter = iw * ih;
    const float uni = area_a + area_b - inter;
    const float iou = inter / uni;

    const float cx1 = fminf(pax1, bx1), cy1 = fminf(pay1, by1);
    const float cx2 = fmaxf(pax2, bx2), cy2 = fmaxf(pay2, by2);
    const float cw = fmaxf(cx2 - cx1, 0.0f), ch = fmaxf(cy2 - cy1, 0.0f);
    const float ac = cw * ch;
    const float giou = iou - (ac - uni) / ac;

    const float cval = 5.0f * cbox + cc - 2.0f * giou;
    cost[(size_t)bq * TT + t] = cval;
    if (ctp) costT[((size_t)b * TT + t) * ctp + q] = cval;
  }
  // fill pad columns with +INF (never win the argmin)
  if (ctp == QP && q < QP - QQ) {
    for (int t = lane; t < TT; t += 64)
      costT[((size_t)b * TT + t) * QP + QQ + q] = INFF;
  }
}

// ------- specialized hungarian: padded costT, ONE WAVE per batch --------
// r14: double-buffered LDS row staging issued at ROW START (full-row
// latency cover, no same-buffer drain), scan directly from LDS (c[15]
// register array deleted -> ~45 live VGPRs, no spill), cmask matched-bit
// (1 readlane) replacing p-extract on the 94% path, v/minv update skipped
// on single-step rows (uniform branch), ballot argmin, way row-stamping.
__global__ void __launch_bounds__(64)
hungarianT_kernel(
    const float* __restrict__ ct,      // [B][T][QP] padded transposed cost
    float* __restrict__ out_q,         // [B][T]
    float* __restrict__ out_t)         // [B][T]
{
  const int b    = blockIdx.x;
  const int lane = threadIdx.x;

  __shared__ __align__(16) float rowbuf[2][QP];
  __shared__ int way_lds[QP];
  __shared__ int qpt[TT];

  const float* __restrict__ base = ct + (size_t)b * TT * QP;

  // invalidate way stamps (decode: (raw>>12)==row; -1 never matches)
#pragma unroll
  for (int k = 0; k < NK; ++k) way_lds[k * 64 + lane] = -1;

  unsigned p4a = 0x64646464u, p4b = 0x64646464u;   // all bytes = TT = 100
  unsigned p4c = 0x64646464u, p4d = 0x64646464u;
  unsigned cmask = 0;           // bit k: column k*64+lane is matched

  float u0 = 0.0f, u1 = 0.0f;   // u[lane], u[64+lane]
  float v[NK];
#pragma unroll
  for (int k = 0; k < NK; ++k) v[k] = 0.0f;

  // prologue: stage row 0 into buffer 0
  stage_row(base, &rowbuf[0][0], lane);

  for (int i = 0; i < TT; ++i) {
    float* bufc = &rowbuf[i & 1][0];

    // row i's stage (issued a full row ago) + any stray path loads: drain
    asm volatile("s_waitcnt vmcnt(0)" ::: "memory");
    // stage row i+1 into the other buffer NOW -> full row of cover
    if (i + 1 < TT)
      stage_row(base + (size_t)(i + 1) * QP, &rowbuf[(i + 1) & 1][0], lane);

    float minv[NK];
#pragma unroll
    for (int k = 0; k < NK; ++k) minv[k] = INFF;
    // umask bits 0..14: used columns; bit30/31: row lane / 64+lane in tree
    unsigned umask = 0;
    const int stamp = i << 12;

    int i0 = i;
    int j0 = VIRT;
    int jfin;
    float ui0 = 0.0f;           // u[i] == 0: row i never in a prior tree

    for (int step = 0; step < 256; ++step) {   // bound: hang insurance
      const bool first = (j0 == VIRT);         // uniform
      if (i0 == lane)      umask |= (1u << 30);
      if (i0 == 64 + lane) umask |= (1u << 31);
      if (!first && (j0 & 63) == lane) umask |= (1u << (j0 >> 6));

      // scan from LDS: minv/way update + per-lane argmin slot
      float lmin  = INFF;
      int   kbest = 0;
#pragma unroll
      for (int k = 0; k < NK; ++k) {
        const float ck  = bufc[k * 64 + lane];
        const bool  uk  = (umask >> k) & 1u;
        const float cur = ck - ui0 - v[k];
        const bool  imp = !uk && (cur < minv[k]);
        if (imp) {
          minv[k] = cur;
          if (!first) way_lds[k * 64 + lane] = stamp | j0;
        }
        const float eff = uk ? INFF : minv[k];
        if (eff < lmin) { lmin = eff; kbest = k; }
      }
      const int lidx = (kbest << 6) + lane;

      // value reduce (6 DPP fmin) -> scalar delta; winner via ballot
      float red = wave_fmin63(lmin);
      const float delta = readlane_f(red, 63);
      const unsigned long long bm = __ballot(lmin == delta);
      const int wl = (int)(__ffsll((long long)bm) - 1);
      const int j1 = __builtin_amdgcn_readlane(lidx, wl);

      // matched check: 1 readlane on cmask (no p extract on 94% path)
      const unsigned cmw =
          (unsigned)__builtin_amdgcn_readlane((int)cmask, j1 & 63);
      const bool fin = !((cmw >> (j1 >> 6)) & 1u);

      if (fin) {
        jfin = j1;
        u0 += ((umask >> 30) & 1u) ? delta : 0.0f;
        u1 += (umask >> 31)        ? delta : 0.0f;
        if (!first) {              // v changes only if used columns exist
#pragma unroll
          for (int k = 0; k < NK; ++k)
            v[k] -= ((umask >> k) & 1u) ? delta : 0.0f;
        }
        break;
      }

      // rare multi-step path (~6% of rows)
      const int i0n = p_get(p4a, p4b, p4c, p4d, j1);
      u0 += ((umask >> 30) & 1u) ? delta : 0.0f;
      u1 += (umask >> 31)        ? delta : 0.0f;
#pragma unroll
      for (int k = 0; k < NK; ++k) {
        const bool uk = (umask >> k) & 1u;
        v[k]    -= uk ? delta : 0.0f;
        minv[k] -= uk ? 0.0f  : delta;
      }
      {
        float us2 = (i0n < 64) ? u0 : u1;
        ui0 = readlane_f(us2, i0n & 63);
      }
      // restage the path row over the current buffer
      asm volatile("s_waitcnt lgkmcnt(0)" ::: "memory");  // reads done
      stage_row(base + (size_t)i0n * QP, bufc, lane);
      asm volatile("s_waitcnt vmcnt(0)" ::: "memory");    // data ready
      j0 = j1;
      i0 = i0n;
    }

    // jfin newly matched: set its cmask bit
    if (lane == (jfin & 63)) cmask |= (1u << (jfin >> 6));

    // augment
    if (j0 == VIRT) {
      P_SET(jfin, i);                   // way[jfin] == VIRT by construction
    } else {
      int j = jfin;
      for (int hop = 0; hop < 256 && j != VIRT; ++hop) {  // bound: insurance
        int raw = way_lds[j];                      // uniform broadcast read
        raw = __builtin_amdgcn_readfirstlane(raw);
        const int jn = ((raw >> 12) == i) ? (raw & 0xFFF) : VIRT;
        const int pj = (jn == VIRT) ? i : p_get(p4a, p4b, p4c, p4d, jn);
        P_SET(j, pj);
        j = jn;
      }
    }
  }

  // q_per_t: query assigned to each target row (pads keep p == TT)
#pragma unroll
  for (int k = 0; k < NK; ++k) {
    const unsigned reg = (k < 4) ? p4a : (k < 8) ? p4b : (k < 12) ? p4c : p4d;
    const int r = (int)((reg >> ((k & 3) * 8)) & 0xFFu);
    const int j = k * 64 + lane;
    if (r < TT) qpt[r] = j;
  }
  __syncthreads();

  // argsort(q_per_t) via rank counting (values are distinct)
  for (int t = lane; t < TT; t += 64) {
    const int myq = qpt[t];
    int rank = 0;
    for (int t2 = 0; t2 < TT; ++t2) rank += (qpt[t2] < myq) ? 1 : 0;
    out_q[b * TT + rank] = (float)myq;
    out_t[b * TT + rank] = (float)t;
  }
}

// ---------------- generic fallback (r7 kernel, verified) ----------------
__global__ void __launch_bounds__(64)
hungarian_kernel(
    const float* __restrict__ cost,    // [B][Q][T]
    const float* __restrict__ costT,   // [B][T][QQ] or nullptr
    float* __restrict__ out_q,
    float* __restrict__ out_t)
{
  const int b    = blockIdx.x;
  const int lane = threadIdx.x;

  __shared__ int p_lds[QQ + 1];
  __shared__ int way_lds[QQ];
  __shared__ int qpt[TT];

  const float* base;
  size_t rs, cs;
  if (costT) { base = costT + (size_t)b * TT * QQ; rs = QQ; cs = 1; }
  else       { base = cost  + (size_t)b * QQ * TT; rs = 1;  cs = TT; }

  for (int j = lane; j <= QQ; j += 64) p_lds[j] = TT;

  float u0 = 0.0f, u1 = 0.0f;
  float v[NK];
#pragma unroll
  for (int k = 0; k < NK; ++k) v[k] = 0.0f;

  float c[NK];
#pragma unroll
  for (int k = 0; k < NK; ++k) {
    const int j = k * 64 + lane;
    c[k] = (j < QQ) ? base[(size_t)j * cs] : 0.0f;
  }

  for (int i = 0; i < TT; ++i) {
    p_lds[QQ] = i;

    float minv[NK];
#pragma unroll
    for (int k = 0; k < NK; ++k) minv[k] = INFF;
    unsigned umask = 0;
    bool t0 = false, t1 = false;

    int i0 = i;
    int j0 = QQ;
    int jfin;

    float us = (i0 < 64) ? u0 : u1;
    float ui0 = readlane_f(us, i0 & 63);

    while (true) {
      t0 = t0 || (i0 == lane);
      t1 = t1 || (i0 == 64 + lane);
      if (j0 != QQ) {
        if ((j0 & 63) == lane) umask |= (1u << (j0 >> 6));
      }

      float lmin = INFF;
      int   lidx = QQ;
#pragma unroll
      for (int k = 0; k < NK; ++k) {
        const int j = k * 64 + lane;
        if (j < QQ && !((umask >> k) & 1u)) {
          const float cur = c[k] - ui0 - v[k];
          if (cur < minv[k]) { minv[k] = cur; way_lds[j] = j0; }
          if (minv[k] < lmin) { lmin = minv[k]; lidx = j; }
        }
      }

      float red = wave_fmin63(lmin);
      const float delta = readlane_f(red, 63);
      int cand = (lmin == delta) ? lidx : 0x7FFFFFFF;
      int redi = wave_imin63(cand);
      const int j1 = __builtin_amdgcn_readlane(redi, 63);

      int i0n = p_lds[j1];
      i0n = __builtin_amdgcn_readfirstlane(i0n);
      const bool fin = (i0n == TT);

      u0 += t0 ? delta : 0.0f;
      u1 += t1 ? delta : 0.0f;
#pragma unroll
      for (int k = 0; k < NK; ++k) {
        const bool uk = (umask >> k) & 1u;
        v[k]    -= uk ? delta : 0.0f;
        minv[k] -= uk ? 0.0f  : delta;
      }

      if (!fin) {
        float us2 = (i0n < 64) ? u0 : u1;
        ui0 = readlane_f(us2, i0n & 63);
#pragma unroll
        for (int k = 0; k < NK; ++k) {
          const int j = k * 64 + lane;
          if (j < QQ) c[k] = base[(size_t)i0n * rs + (size_t)j * cs];
        }
      }
      asm volatile("" ::: "memory");

      if (fin) { jfin = j1; break; }
      j0 = j1;
      i0 = i0n;
    }

    if (i + 1 < TT) {
#pragma unroll
      for (int k = 0; k < NK; ++k) {
        const int jj = k * 64 + lane;
        if (jj < QQ) c[k] = base[(size_t)(i + 1) * rs + (size_t)jj * cs];
      }
    }

    int j = jfin;
    while (j != QQ) {
      const int jn = way_lds[j];
      const int pj = p_lds[jn];
      p_lds[j] = pj;
      j = jn;
    }
    asm volatile("" ::: "memory");
  }

#pragma unroll
  for (int k = 0; k < NK; ++k) {
    const int j = k * 64 + lane;
    if (j < QQ) {
      const int r = p_lds[j];
      if (r < TT) qpt[r] = j;
    }
  }
  __syncthreads();

  for (int t = lane; t < TT; t += 64) {
    const int myq = qpt[t];
    int rank = 0;
    for (int t2 = 0; t2 < TT; ++t2) rank += (qpt[t2] < myq) ? 1 : 0;
    out_q[b * TT + rank] = (float)myq;
    out_t[b * TT + rank] = (float)t;
  }
}

extern "C" void kernel_launch(void* const* d_in, const int* in_sizes, int n_in,
                              void* d_out, int out_size, void* d_ws, size_t ws_size,
                              hipStream_t stream) {
  const float* logits  = (const float*)d_in[0];
  const float* pboxes  = (const float*)d_in[1];
  const int*   tlabels = (const int*)d_in[2];
  const float* tboxes  = (const float*)d_in[3];

  float* out  = (float*)d_out;
  float* cost = out;                               // [B][Q][T]
  float* oq   = out + (size_t)BB * QQ * TT;        // [B][T]
  float* ot   = oq + (size_t)BB * TT;              // [B][T]

  const size_t padded_bytes = (size_t)BB * TT * QP * sizeof(float);
  const size_t plain_bytes  = (size_t)BB * TT * QQ * sizeof(float);

  if (ws_size >= padded_bytes) {
    float* costT = (float*)d_ws;
    hipLaunchKernelGGL(cost_kernel, dim3(BB * QQ), dim3(64), 0, stream,
                       logits, pboxes, tlabels, tboxes, cost, costT, QP);
    hipLaunchKernelGGL(hungarianT_kernel, dim3(BB), dim3(64), 0, stream,
                       costT, oq, ot);
  } else if (ws_size >= plain_bytes) {
    float* costT = (float*)d_ws;
    hipLaunchKernelGGL(cost_kernel, dim3(BB * QQ), dim3(64), 0, stream,
                       logits, pboxes, tlabels, tboxes, cost, costT, QQ);
    hipLaunchKernelGGL(hungarian_kernel, dim3(BB), dim3(64), 0, stream,
                       cost, costT, oq, ot);
  } else {
    hipLaunchKernelGGL(cost_kernel, dim3(BB * QQ), dim3(64), 0, stream,
                       logits, pboxes, tlabels, tboxes, cost, (float*)nullptr, 0);
    hipLaunchKernelGGL(hungarian_kernel, dim3(BB), dim3(64), 0, stream,
                       cost, (const float*)nullptr, oq, ot);
  }
}

// Round 15
// 191.205 us; speedup vs baseline: 1.2959x; 1.2311x over previous
//
#include <hip/hip_runtime.h>

#define BB 16
#define QQ 900
#define QP 960           // padded column count = 15*64 (pad cols hold +INF)
#define VIRT QP          // virtual start column index
#define CC 92
#define TT 100
#define INFF 1e18f
#define NK 15            // QP / 64

// ---- DPP wave64 reductions (VALU latency, no DS ops) -------------------
#define DPP_STEP_F(x, ctrl, OP)                                             \
  do {                                                                      \
    float _o = __int_as_float(__builtin_amdgcn_update_dpp(                  \
        __float_as_int(x), __float_as_int(x), (ctrl), 0xF, 0xF, false));    \
    (x) = OP((x), _o);                                                      \
  } while (0)

__device__ __forceinline__ float wave_fmin63(float x) {
  DPP_STEP_F(x, 0xB1, fminf);   // xor 1
  DPP_STEP_F(x, 0x4E, fminf);   // xor 2
  DPP_STEP_F(x, 0x141, fminf);  // xor 4
  DPP_STEP_F(x, 0x140, fminf);  // xor 8
  DPP_STEP_F(x, 0x142, fminf);  // row_bcast15
  DPP_STEP_F(x, 0x143, fminf);  // row_bcast31
  return x;                     // lane 63 valid
}
__device__ __forceinline__ float wave_fmax63(float x) {
  DPP_STEP_F(x, 0xB1, fmaxf);
  DPP_STEP_F(x, 0x4E, fmaxf);
  DPP_STEP_F(x, 0x141, fmaxf);
  DPP_STEP_F(x, 0x140, fmaxf);
  DPP_STEP_F(x, 0x142, fmaxf);
  DPP_STEP_F(x, 0x143, fmaxf);
  return x;
}
__device__ __forceinline__ float wave_fadd63(float x) {
#define ADDF(a, b) ((a) + (b))
  DPP_STEP_F(x, 0xB1, ADDF);
  DPP_STEP_F(x, 0x4E, ADDF);
  DPP_STEP_F(x, 0x141, ADDF);
  DPP_STEP_F(x, 0x140, ADDF);
  DPP_STEP_F(x, 0x142, ADDF);
  DPP_STEP_F(x, 0x143, ADDF);
#undef ADDF
  return x;
}
__device__ __forceinline__ int wave_imin63(int x) {
  {int _o=__builtin_amdgcn_update_dpp(x,x,0xB1,0xF,0xF,false); x=_o<x?_o:x;}
  {int _o=__builtin_amdgcn_update_dpp(x,x,0x4E,0xF,0xF,false); x=_o<x?_o:x;}
  {int _o=__builtin_amdgcn_update_dpp(x,x,0x141,0xF,0xF,false);x=_o<x?_o:x;}
  {int _o=__builtin_amdgcn_update_dpp(x,x,0x140,0xF,0xF,false);x=_o<x?_o:x;}
  {int _o=__builtin_amdgcn_update_dpp(x,x,0x142,0xF,0xF,false);x=_o<x?_o:x;}
  {int _o=__builtin_amdgcn_update_dpp(x,x,0x143,0xF,0xF,false);x=_o<x?_o:x;}
  return x;
}

// ---------------- cost kernel: one WAVE per (b,q) ----------------
// ctp = costT column stride (QP padded, QQ unpadded, 0 = no costT)
__global__ __launch_bounds__(64) void cost_kernel(
    const float* __restrict__ logits,   // [B][Q][C]
    const float* __restrict__ pboxes,   // [B][Q][4]
    const int*   __restrict__ tlabels,  // [B][T]
    const float* __restrict__ tboxes,   // [B][T][4]
    float* __restrict__ cost,           // [B][Q][T]
    float* __restrict__ costT,          // [B][T][ctp] or nullptr
    int ctp)
{
  const int bq   = blockIdx.x;          // b*QQ + q
  const int b    = bq / QQ;
  const int q    = bq - b * QQ;
  const int lane = threadIdx.x;

  __shared__ float sl[CC];

  const float a = logits[(size_t)bq * CC + lane];
  const float bb2 = (lane < CC - 64)
                        ? logits[(size_t)bq * CC + 64 + lane]
                        : -3.402823466e38f;

  float mx = fmaxf(a, bb2);
  mx = wave_fmax63(mx);
  const float m = __int_as_float(
      __builtin_amdgcn_readlane(__float_as_int(mx), 63));

  const float e0 = expf(a - m);
  const float e1 = (lane < CC - 64) ? expf(bb2 - m) : 0.0f;
  sl[lane] = e0;
  if (lane < CC - 64) sl[64 + lane] = e1;

  float sm = e0 + e1;
  sm = wave_fadd63(sm);
  const float ssum = __int_as_float(
      __builtin_amdgcn_readlane(__float_as_int(sm), 63));

  const float4 pbv = ((const float4*)pboxes)[bq];
  const float pax1 = pbv.x - 0.5f * pbv.z, pay1 = pbv.y - 0.5f * pbv.w;
  const float pax2 = pbv.x + 0.5f * pbv.z, pay2 = pbv.y + 0.5f * pbv.w;
  const float area_a = (pax2 - pax1) * (pay2 - pay1);

  for (int t = lane; t < TT; t += 64) {
    const int lab = tlabels[b * TT + t];
    const float cc = -(sl[lab] / ssum);

    const float4 tb = ((const float4*)tboxes)[b * TT + t];
    const float cbox = fabsf(pbv.x - tb.x) + fabsf(pbv.y - tb.y) +
                       fabsf(pbv.z - tb.z) + fabsf(pbv.w - tb.w);

    const float bx1 = tb.x - 0.5f * tb.z, by1 = tb.y - 0.5f * tb.w;
    const float bx2 = tb.x + 0.5f * tb.z, by2 = tb.y + 0.5f * tb.w;
    const float area_b = (bx2 - bx1) * (by2 - by1);

    const float ltx = fmaxf(pax1, bx1), lty = fmaxf(pay1, by1);
    const float rbx = fminf(pax2, bx2), rby = fminf(pay2, by2);
    const float iw = fmaxf(rbx - ltx, 0.0f), ih = fmaxf(rby - lty, 0.0f);
    const float inter = iw * ih;
    const float uni = area_a + area_b - inter;
    const float iou = inter / uni;

    const float cx1 = fminf(pax1, bx1), cy1 = fminf(pay1, by1);
    const float cx2 = fmaxf(pax2, bx2), cy2 = fmaxf(pay2, by2);
    const float cw = fmaxf(cx2 - cx1, 0.0f), ch = fmaxf(cy2 - cy1, 0.0f);
    const float ac = cw * ch;
    const float giou = iou - (ac - uni) / ac;

    const float cval = 5.0f * cbox + cc - 2.0f * giou;
    cost[(size_t)bq * TT + t] = cval;
    if (ctp) costT[((size_t)b * TT + t) * ctp + q] = cval;
  }
  // fill pad columns with +INF (never win the argmin)
  if (ctp == QP && q < QP - QQ) {
    for (int t = lane; t < TT; t += 64)
      costT[((size_t)b * TT + t) * QP + QQ + q] = INFF;
  }
}

// ------- specialized hungarian: padded costT, ONE WAVE per batch --------
// Column j in [0,QP) owned by lane (j&63), slot (j>>6); pads hold +INF.
// Register state: c[15]+minv[15]+v[15]=45 VGPR + ~12 temps -> fits the
// 64-VGPR cap with ZERO spill. Row base address is scalar; way/p in LDS,
// u in 2 regs + readlane. This exact configuration is the empirical
// champion (r7: 172us); LDS-scan variants (r10/r11/r14) and micro-opt
// bundles (r12/r13) all regressed 5-35%.
__global__ void __launch_bounds__(64, 1)
__attribute__((amdgpu_waves_per_eu(1)))
hungarianT_kernel(
    const float* __restrict__ ct,      // [B][T][QP] padded transposed cost
    float* __restrict__ out_q,         // [B][T]
    float* __restrict__ out_t)         // [B][T]
{
  const int b    = blockIdx.x;
  const int lane = threadIdx.x;

  __shared__ int p_lds[QP + 1];
  __shared__ int way_lds[QP];
  __shared__ int qpt[TT];

  const float* __restrict__ base = ct + (size_t)b * TT * QP;

  for (int j = lane; j <= QP; j += 64) p_lds[j] = TT;

  float u0 = 0.0f, u1 = 0.0f;   // u[lane], u[64+lane]
  float v[NK];
#pragma unroll
  for (int k = 0; k < NK; ++k) v[k] = 0.0f;

  // prefetch row 0
  float c[NK];
#pragma unroll
  for (int k = 0; k < NK; ++k) c[k] = base[k * 64 + lane];

  for (int i = 0; i < TT; ++i) {
    p_lds[VIRT] = i;             // all lanes, same addr, same value

    float minv[NK];
#pragma unroll
    for (int k = 0; k < NK; ++k) minv[k] = INFF;
    unsigned umask = 0;          // used columns (my lane's 15 slots)
    bool t0 = false, t1 = false; // rows in tree: lane, 64+lane

    int i0 = i;
    int j0 = VIRT;
    int jfin;

    float us = (i0 < 64) ? u0 : u1;
    float ui0 = __int_as_float(
        __builtin_amdgcn_readlane(__float_as_int(us), i0 & 63));

    while (true) {
      // add row i0 to tree; mark column j0 used (real cols only)
      t0 = t0 || (i0 == lane);
      t1 = t1 || (i0 == 64 + lane);
      if (j0 != VIRT && (j0 & 63) == lane) umask |= (1u << (j0 >> 6));

      // scan: minv/way update + per-lane argmin as 4-bit slot index
      float lmin  = INFF;
      int   kbest = 0;
#pragma unroll
      for (int k = 0; k < NK; ++k) {
        const bool  uk  = (umask >> k) & 1u;
        const float cur = c[k] - ui0 - v[k];
        const bool  imp = !uk && (cur < minv[k]);
        if (imp) { minv[k] = cur; way_lds[k * 64 + lane] = j0; }
        const float eff = uk ? INFF : minv[k];
        if (eff < lmin) { lmin = eff; kbest = k; }
      }
      const int lidx = kbest * 64 + lane;

      // DPP argmin: value reduce, then lowest index among exact minima
      float red = wave_fmin63(lmin);
      const float delta = __int_as_float(
          __builtin_amdgcn_readlane(__float_as_int(red), 63));
      int cand = (lmin == delta) ? lidx : 0x7FFFFFFF;
      int redi = wave_imin63(cand);
      const int j1 = __builtin_amdgcn_readlane(redi, 63);

      // row matched to j1 (broadcast LDS read; only DS read in the loop)
      int i0n = p_lds[j1];
      i0n = __builtin_amdgcn_readfirstlane(i0n);
      const bool fin = (i0n == TT);

      // prefetch next scan row ASAP (scalar row base, imm offsets)
      if (!fin) {
        const float* __restrict__ row = base + (size_t)i0n * QP;
#pragma unroll
        for (int k = 0; k < NK; ++k) c[k] = row[k * 64 + lane];
      }

      // potential updates: pure register ops, overlap the load latency
      u0 += t0 ? delta : 0.0f;
      u1 += t1 ? delta : 0.0f;
#pragma unroll
      for (int k = 0; k < NK; ++k) {
        const bool uk = (umask >> k) & 1u;
        v[k]    -= uk ? delta : 0.0f;
        minv[k] -= uk ? 0.0f  : delta;
      }

      if (fin) { jfin = j1; break; }
      // u[i0n] for next scan (i0n not yet in tree -> unaffected by update)
      float us2 = (i0n < 64) ? u0 : u1;
      ui0 = __int_as_float(
          __builtin_amdgcn_readlane(__float_as_int(us2), i0n & 63));
      j0 = j1;
      i0 = i0n;
    }

    // prefetch row i+1 (next Dijkstra start) under the augment walk
    if (i + 1 < TT) {
      const float* __restrict__ row = base + (size_t)(i + 1) * QP;
#pragma unroll
      for (int k = 0; k < NK; ++k) c[k] = row[k * 64 + lane];
    }

    // augment along the way chain (uniform serial walk)
    int j = jfin;
    while (j != VIRT) {
      const int jn = way_lds[j];
      const int pj = p_lds[jn];  // jn may be VIRT -> p_lds[VIRT] == i
      p_lds[j] = pj;             // all lanes same addr, same value
      j = jn;
    }
    asm volatile("" ::: "memory");
  }

  // q_per_t: query assigned to each target row (pads have p == TT)
#pragma unroll
  for (int k = 0; k < NK; ++k) {
    const int j = k * 64 + lane;
    const int r = p_lds[j];
    if (r < TT) qpt[r] = j;
  }
  __syncthreads();

  // argsort(q_per_t) via rank counting (values are distinct)
  for (int t = lane; t < TT; t += 64) {
    const int myq = qpt[t];
    int rank = 0;
    for (int t2 = 0; t2 < TT; ++t2) rank += (qpt[t2] < myq) ? 1 : 0;
    out_q[b * TT + rank] = (float)myq;
    out_t[b * TT + rank] = (float)t;
  }
}

// ---------------- generic fallback (verified) ----------------
__global__ void __launch_bounds__(64)
hungarian_kernel(
    const float* __restrict__ cost,    // [B][Q][T]
    const float* __restrict__ costT,   // [B][T][QQ] or nullptr
    float* __restrict__ out_q,
    float* __restrict__ out_t)
{
  const int b    = blockIdx.x;
  const int lane = threadIdx.x;

  __shared__ int p_lds[QQ + 1];
  __shared__ int way_lds[QQ];
  __shared__ int qpt[TT];

  const float* base;
  size_t rs, cs;
  if (costT) { base = costT + (size_t)b * TT * QQ; rs = QQ; cs = 1; }
  else       { base = cost  + (size_t)b * QQ * TT; rs = 1;  cs = TT; }

  for (int j = lane; j <= QQ; j += 64) p_lds[j] = TT;

  float u0 = 0.0f, u1 = 0.0f;
  float v[NK];
#pragma unroll
  for (int k = 0; k < NK; ++k) v[k] = 0.0f;

  float c[NK];
#pragma unroll
  for (int k = 0; k < NK; ++k) {
    const int j = k * 64 + lane;
    c[k] = (j < QQ) ? base[(size_t)j * cs] : 0.0f;
  }

  for (int i = 0; i < TT; ++i) {
    p_lds[QQ] = i;

    float minv[NK];
#pragma unroll
    for (int k = 0; k < NK; ++k) minv[k] = INFF;
    unsigned umask = 0;
    bool t0 = false, t1 = false;

    int i0 = i;
    int j0 = QQ;
    int jfin;

    float us = (i0 < 64) ? u0 : u1;
    float ui0 = __int_as_float(
        __builtin_amdgcn_readlane(__float_as_int(us), i0 & 63));

    while (true) {
      t0 = t0 || (i0 == lane);
      t1 = t1 || (i0 == 64 + lane);
      if (j0 != QQ) {
        if ((j0 & 63) == lane) umask |= (1u << (j0 >> 6));
      }

      float lmin = INFF;
      int   lidx = QQ;
#pragma unroll
      for (int k = 0; k < NK; ++k) {
        const int j = k * 64 + lane;
        if (j < QQ && !((umask >> k) & 1u)) {
          const float cur = c[k] - ui0 - v[k];
          if (cur < minv[k]) { minv[k] = cur; way_lds[j] = j0; }
          if (minv[k] < lmin) { lmin = minv[k]; lidx = j; }
        }
      }

      float red = wave_fmin63(lmin);
      const float delta = __int_as_float(
          __builtin_amdgcn_readlane(__float_as_int(red), 63));
      int cand = (lmin == delta) ? lidx : 0x7FFFFFFF;
      int redi = wave_imin63(cand);
      const int j1 = __builtin_amdgcn_readlane(redi, 63);

      int i0n = p_lds[j1];
      i0n = __builtin_amdgcn_readfirstlane(i0n);
      const bool fin = (i0n == TT);

      u0 += t0 ? delta : 0.0f;
      u1 += t1 ? delta : 0.0f;
#pragma unroll
      for (int k = 0; k < NK; ++k) {
        const bool uk = (umask >> k) & 1u;
        v[k]    -= uk ? delta : 0.0f;
        minv[k] -= uk ? 0.0f  : delta;
      }

      if (!fin) {
        float us2 = (i0n < 64) ? u0 : u1;
        ui0 = __int_as_float(
            __builtin_amdgcn_readlane(__float_as_int(us2), i0n & 63));
#pragma unroll
        for (int k = 0; k < NK; ++k) {
          const int j = k * 64 + lane;
          if (j < QQ) c[k] = base[(size_t)i0n * rs + (size_t)j * cs];
        }
      }
      asm volatile("" ::: "memory");

      if (fin) { jfin = j1; break; }
      j0 = j1;
      i0 = i0n;
    }

    if (i + 1 < TT) {
#pragma unroll
      for (int k = 0; k < NK; ++k) {
        const int jj = k * 64 + lane;
        if (jj < QQ) c[k] = base[(size_t)(i + 1) * rs + (size_t)jj * cs];
      }
    }

    int j = jfin;
    while (j != QQ) {
      const int jn = way_lds[j];
      const int pj = p_lds[jn];
      p_lds[j] = pj;
      j = jn;
    }
    asm volatile("" ::: "memory");
  }

#pragma unroll
  for (int k = 0; k < NK; ++k) {
    const int j = k * 64 + lane;
    if (j < QQ) {
      const int r = p_lds[j];
      if (r < TT) qpt[r] = j;
    }
  }
  __syncthreads();

  for (int t = lane; t < TT; t += 64) {
    const int myq = qpt[t];
    int rank = 0;
    for (int t2 = 0; t2 < TT; ++t2) rank += (qpt[t2] < myq) ? 1 : 0;
    out_q[b * TT + rank] = (float)myq;
    out_t[b * TT + rank] = (float)t;
  }
}

extern "C" void kernel_launch(void* const* d_in, const int* in_sizes, int n_in,
                              void* d_out, int out_size, void* d_ws, size_t ws_size,
                              hipStream_t stream) {
  const float* logits  = (const float*)d_in[0];
  const float* pboxes  = (const float*)d_in[1];
  const int*   tlabels = (const int*)d_in[2];
  const float* tboxes  = (const float*)d_in[3];

  float* out  = (float*)d_out;
  float* cost = out;                               // [B][Q][T]
  float* oq   = out + (size_t)BB * QQ * TT;        // [B][T]
  float* ot   = oq + (size_t)BB * TT;              // [B][T]

  const size_t padded_bytes = (size_t)BB * TT * QP * sizeof(float);
  const size_t plain_bytes  = (size_t)BB * TT * QQ * sizeof(float);

  if (ws_size >= padded_bytes) {
    float* costT = (float*)d_ws;
    hipLaunchKernelGGL(cost_kernel, dim3(BB * QQ), dim3(64), 0, stream,
                       logits, pboxes, tlabels, tboxes, cost, costT, QP);
    hipLaunchKernelGGL(hungarianT_kernel, dim3(BB), dim3(64), 0, stream,
                       costT, oq, ot);
  } else if (ws_size >= plain_bytes) {
    float* costT = (float*)d_ws;
    hipLaunchKernelGGL(cost_kernel, dim3(BB * QQ), dim3(64), 0, stream,
                       logits, pboxes, tlabels, tboxes, cost, costT, QQ);
    hipLaunchKernelGGL(hungarian_kernel, dim3(BB), dim3(64), 0, stream,
                       cost, costT, oq, ot);
  } else {
    hipLaunchKernelGGL(cost_kernel, dim3(BB * QQ), dim3(64), 0, stream,
                       logits, pboxes, tlabels, tboxes, cost, (float*)nullptr, 0);
    hipLaunchKernelGGL(hungarian_kernel, dim3(BB), dim3(64), 0, stream,
                       cost, (const float*)nullptr, oq, ot);
  }
}